// Round 10
// baseline (200.058 us; speedup 1.0000x reference)
//
#include <hip/hip_runtime.h>
#include <hip/hip_bf16.h>

typedef __attribute__((ext_vector_type(8))) short short8;
typedef __attribute__((ext_vector_type(4))) short short4v;
typedef __attribute__((ext_vector_type(4))) float floatx4;

union BF8 { short8 v; __hip_bfloat16 b[8]; };
union BF4U { ushort4 u; __hip_bfloat16 b[4]; };
union S4U { uint2 u; short4v v; };

__device__ __forceinline__ short8 load8(const __hip_bfloat16* p) {
    return *reinterpret_cast<const short8*>(p);
}
__device__ __forceinline__ short4v load4(const __hip_bfloat16* p) {
    return *reinterpret_cast<const short4v*>(p);
}

// pack two fp32 -> two bf16 (round-half-up) in one dword: [lo]=a, [hi]=b
__device__ __forceinline__ unsigned pack_bf16(float a, float b) {
    unsigned ua = __float_as_uint(a) + 0x8000u;
    unsigned ub = __float_as_uint(b) + 0x8000u;
    return __builtin_amdgcn_perm(ub, ua, 0x07060302u);
}

// 2^x (v_exp_f32); scale/log2e pre-folded into Q
__device__ __forceinline__ float exp2_fast(float x) {
#if __has_builtin(__builtin_amdgcn_exp2f)
    return __builtin_amdgcn_exp2f(x);
#else
    return __expf(x * 0.6931471805599453f);
#endif
}

// 16x16x16 bf16 MFMA (K=16): the C-layout of a 16x16 S^T tile (lane: k=lq*4+r,
// q=lr) IS this shape's A-layout -> PV needs no cross-lane transform.
#if __has_builtin(__builtin_amdgcn_mfma_f32_16x16x16_bf16)
__device__ __forceinline__ floatx4 mfma16(short4v a, short4v b, floatx4 c) {
    return __builtin_amdgcn_mfma_f32_16x16x16_bf16(a, b, c, 0, 0, 0);
}
#elif __has_builtin(__builtin_amdgcn_mfma_f32_16x16x16bf16_1k)
__device__ __forceinline__ floatx4 mfma16(short4v a, short4v b, floatx4 c) {
    return __builtin_amdgcn_mfma_f32_16x16x16bf16_1k(a, b, c, 0, 0, 0);
}
#else
__device__ __forceinline__ floatx4 mfma16(short4v a, short4v b, floatx4 c) {
    asm volatile("v_mfma_f32_16x16x16_bf16 %0, %1, %2, %0"
                 : "+v"(c) : "v"(a), "v"(b));
    return c;
}
#endif

// async global->LDS, 16B per lane. LDS dest must be wave-uniform base + lane*16.
__device__ __forceinline__ void gload_lds16(const __hip_bfloat16* g, __hip_bfloat16* l) {
    __builtin_amdgcn_global_load_lds(
        (const __attribute__((address_space(1))) void*)g,
        (__attribute__((address_space(3))) void*)l, 16, 0, 0);
}

// -------- fp32 -> bf16 casts: y=0 hidden states (1M float4), y=1 the 4 weights ----
__global__ __launch_bounds__(256) void cast_all(const float* __restrict__ hs,
                                                const float* __restrict__ wq,
                                                const float* __restrict__ wk,
                                                const float* __restrict__ wv,
                                                const float* __restrict__ wo,
                                                __hip_bfloat16* __restrict__ Xb,
                                                __hip_bfloat16* __restrict__ Wb) {
    int i = blockIdx.x * 256 + threadIdx.x;
    const float* src;
    __hip_bfloat16* dst;
    if (blockIdx.y == 0) {
        src = hs; dst = Xb;
    } else {
        int m = i >> 18;
        src = (m == 0) ? wq : (m == 1) ? wk : (m == 2) ? wv : wo;
        src -= (size_t)m * 1048576;
        dst = Wb;
    }
    float4 v = reinterpret_cast<const float4*>(src)[i];
    BF4U u;
    u.b[0] = __float2bfloat16(v.x);
    u.b[1] = __float2bfloat16(v.y);
    u.b[2] = __float2bfloat16(v.z);
    u.b[3] = __float2bfloat16(v.w);
    reinterpret_cast<ushort4*>(dst)[i] = u.u;
}

// ------- fused QKV projection GEMM (B^T form), 128x128 tiles, BK=32 --------------
// z=0: Q = X.Wq^T, per-head L2 norm, scaled by qkf*log2e -> Qb [4096,1024]
// z=1: K = X.Wk^T, per-head L2 norm                      -> Kb [4096,1024]
// z=2: Vt = (Wv.X^T) stored row-major = V^T directly     -> Vt [B=2][1024 e][2048 s]
__global__ __launch_bounds__(256) void gemm_qkv(const __hip_bfloat16* __restrict__ Xb,
                                                const __hip_bfloat16* __restrict__ Wqkv,
                                                __hip_bfloat16* __restrict__ Qb,
                                                __hip_bfloat16* __restrict__ Kb,
                                                __hip_bfloat16* __restrict__ Vt,
                                                const float* __restrict__ scale_p) {
    __shared__ __hip_bfloat16 lA[128 * 32];
    __shared__ __hip_bfloat16 lB[128 * 32];
    const int z = blockIdx.z;
    const __hip_bfloat16* A;
    const __hip_bfloat16* B;
    int m0, n0;
    if (z < 2) {
        A = Xb;
        B = Wqkv + (size_t)z * 1048576;
        m0 = blockIdx.x * 128;
        n0 = blockIdx.y * 128;
    } else {
        A = Wqkv + (size_t)2 * 1048576;
        B = Xb;
        m0 = (blockIdx.x & 7) * 128;
        n0 = (((blockIdx.x >> 3) * 8) + blockIdx.y) * 128;
    }
    const int Kd = 1024;
    const int t = threadIdx.x;
    const int w = t >> 6, l = t & 63;
    const int wr = (w >> 1) * 64, wc = (w & 1) * 64;
    const int lr = l & 15, lq = l >> 4;

    const floatx4 zero4 = {0.f, 0.f, 0.f, 0.f};
    floatx4 acc[4][4];
#pragma unroll
    for (int mt = 0; mt < 4; ++mt)
#pragma unroll
        for (int nt = 0; nt < 4; ++nt) acc[mt][nt] = zero4;

    for (int k0 = 0; k0 < Kd; k0 += 32) {
#pragma unroll
        for (int i = 0; i < 2; ++i) {
            int flat = t + i * 256;
            int row = flat >> 2, ch = flat & 3;
            gload_lds16(A + (size_t)(m0 + row) * Kd + k0 + ch * 8, lA + flat * 8);
            gload_lds16(B + (size_t)(n0 + row) * Kd + k0 + ch * 8, lB + flat * 8);
        }
        __syncthreads();
        short8 af[4], bfr[4];
#pragma unroll
        for (int mt = 0; mt < 4; ++mt)
            af[mt] = load8(lA + (wr + mt * 16 + lr) * 32 + lq * 8);
#pragma unroll
        for (int nt = 0; nt < 4; ++nt)
            bfr[nt] = load8(lB + (wc + nt * 16 + lr) * 32 + lq * 8);
#pragma unroll
        for (int mt = 0; mt < 4; ++mt)
#pragma unroll
            for (int nt = 0; nt < 4; ++nt)
                acc[mt][nt] = __builtin_amdgcn_mfma_f32_16x16x32_bf16(
                    af[mt], bfr[nt], acc[mt][nt], 0, 0, 0);
        __syncthreads();
    }

    if (z < 2) {
        const float fac = (z == 0) ? (*scale_p * 1.44269504f) : 1.0f;
#pragma unroll
        for (int mt = 0; mt < 4; ++mt)
#pragma unroll
            for (int r = 0; r < 4; ++r) {
                float ss = 0.f;
#pragma unroll
                for (int nt = 0; nt < 4; ++nt) {
                    float v = acc[mt][nt][r];
                    ss += v * v;
                }
                ss += __shfl_xor(ss, 1, 64);
                ss += __shfl_xor(ss, 2, 64);
                ss += __shfl_xor(ss, 4, 64);
                ss += __shfl_xor(ss, 8, 64);
                float inv = fac / (sqrtf(ss) + 1e-6f);
#pragma unroll
                for (int nt = 0; nt < 4; ++nt) acc[mt][nt][r] *= inv;
            }
        __hip_bfloat16* C = (z == 0) ? Qb : Kb;
#pragma unroll
        for (int mt = 0; mt < 4; ++mt)
#pragma unroll
            for (int nt = 0; nt < 4; ++nt)
#pragma unroll
                for (int r = 0; r < 4; ++r) {
                    int row = m0 + wr + mt * 16 + lq * 4 + r;
                    int col = n0 + wc + nt * 16 + lr;
                    C[(size_t)row * 1024 + col] = __float2bfloat16(acc[mt][nt][r]);
                }
    } else {
#pragma unroll
        for (int mt = 0; mt < 4; ++mt)
#pragma unroll
            for (int nt = 0; nt < 4; ++nt)
#pragma unroll
                for (int r = 0; r < 4; ++r) {
                    int e = m0 + wr + mt * 16 + lq * 4 + r;
                    int col = n0 + wc + nt * 16 + lr;
                    int bb = col >> 11, s = col & 2047;
                    Vt[(size_t)bb * 2097152 + (size_t)e * 2048 + s] =
                        __float2bfloat16(acc[mt][nt][r]);
                }
    }
}

// ---------------- out-projection: C[4096,1024] = A . Wo^T, 64x128 tiles ----------
// 512 blocks -> 2/CU (the 128x128 version had only 256 blocks = 1/CU: barrier
// drains fully exposed).
__global__ __launch_bounds__(256) void gemm_out(const __hip_bfloat16* __restrict__ A,
                                                const __hip_bfloat16* __restrict__ B,
                                                float* __restrict__ C) {
    __shared__ __hip_bfloat16 lA[64 * 32];
    __shared__ __hip_bfloat16 lB[128 * 32];
    const int Kd = 1024, N = 1024;
    const int t = threadIdx.x;
    const int m0 = blockIdx.x * 64, n0 = blockIdx.y * 128;
    const int w = t >> 6, l = t & 63;
    const int wr = (w >> 1) * 32, wc = (w & 1) * 64;
    const int lr = l & 15, lq = l >> 4;

    const floatx4 zero4 = {0.f, 0.f, 0.f, 0.f};
    floatx4 acc[2][4];
#pragma unroll
    for (int mt = 0; mt < 2; ++mt)
#pragma unroll
        for (int nt = 0; nt < 4; ++nt) acc[mt][nt] = zero4;

    for (int k0 = 0; k0 < Kd; k0 += 32) {
        gload_lds16(A + (size_t)(m0 + (t >> 2)) * Kd + k0 + (t & 3) * 8, lA + t * 8);
#pragma unroll
        for (int i = 0; i < 2; ++i) {
            int flat = t + i * 256;
            gload_lds16(B + (size_t)(n0 + (flat >> 2)) * Kd + k0 + (flat & 3) * 8,
                        lB + flat * 8);
        }
        __syncthreads();
        short8 af[2], bfr[4];
#pragma unroll
        for (int mt = 0; mt < 2; ++mt)
            af[mt] = load8(lA + (wr + mt * 16 + lr) * 32 + lq * 8);
#pragma unroll
        for (int nt = 0; nt < 4; ++nt)
            bfr[nt] = load8(lB + (wc + nt * 16 + lr) * 32 + lq * 8);
#pragma unroll
        for (int mt = 0; mt < 2; ++mt)
#pragma unroll
            for (int nt = 0; nt < 4; ++nt)
                acc[mt][nt] = __builtin_amdgcn_mfma_f32_16x16x32_bf16(
                    af[mt], bfr[nt], acc[mt][nt], 0, 0, 0);
        __syncthreads();
    }
#pragma unroll
    for (int mt = 0; mt < 2; ++mt)
#pragma unroll
        for (int nt = 0; nt < 4; ++nt)
#pragma unroll
            for (int r = 0; r < 4; ++r) {
                int row = m0 + wr + mt * 16 + lq * 4 + r;
                int col = n0 + wc + nt * 16 + lr;
                C[(size_t)row * N + col] = acc[mt][nt][r];
            }
}

// ---------------- causal flash attention: cooperative superstep staging ----------
// Block stages a 128-wide k-slab (K 16 KB + V 16 KB, coalesced, XOR-swizzled)
// shared by all 4 waves; wave w consumes k-step base+w against all 64 q-rows
// (keeps R8's LDS-read amortization, kills the 4x per-wave DMA duplication).
// Q is LDS-staged once per tile. 17 supersteps per block (pair-uniform).
__global__ __launch_bounds__(256) void flash_attn(const __hip_bfloat16* __restrict__ Q,
                                                  const __hip_bfloat16* __restrict__ K,
                                                  const __hip_bfloat16* __restrict__ Vt,
                                                  __hip_bfloat16* __restrict__ O) {
    const int S = 2048, D = 1024;
    __shared__ __align__(16) char smem[32768];  // kbuf 16K | vbuf 16K; epi reuses 20K
    __hip_bfloat16* kbuf = reinterpret_cast<__hip_bfloat16*>(smem);
    __hip_bfloat16* vbuf = reinterpret_cast<__hip_bfloat16*>(smem + 16384);
    float* buf = reinterpret_cast<float*>(smem);
    const int t = threadIdx.x;
    const int w = t >> 6, l = t & 63;
    const int lr = l & 15, lq = l >> 4;
    const int id = blockIdx.x;
    const int bh = (id & 7) * 4 + ((id >> 3) & 3);  // 4 heads per XCD (id%8 ~ XCD)
    const int pr = id >> 5;                          // 0..15 pair index
    const int b = bh >> 4, h = bh & 15;
    const __hip_bfloat16* Qb = Q + ((size_t)b * S) * D + h * 64;
    const __hip_bfloat16* Kb = K + ((size_t)b * S) * D + h * 64;
    const __hip_bfloat16* Vb = Vt + (size_t)bh * 64 * S;

#pragma unroll 1
    for (int tile = 0; tile < 2; ++tile) {
        const int jq = (tile == 0) ? (31 - pr) : pr;
        const int q0 = jq * 64;

        // ---- stage Q tile (64x64) into kbuf, read fragments, release ----
        __syncthreads();  // prior use of smem done (epilogue reads / first entry)
#pragma unroll
        for (int i = 0; i < 2; ++i) {
            int flat = t + i * 256;
            int row = flat >> 3, sg = (flat & 7) ^ (row & 7);
            gload_lds16(Qb + (size_t)(q0 + row) * D + sg * 8, kbuf + flat * 8);
        }
        __syncthreads();
        short8 bq[4][2];
#pragma unroll
        for (int nt = 0; nt < 4; ++nt)
#pragma unroll
            for (int kt = 0; kt < 2; ++kt) {
                const int rl = nt * 16 + lr;
                const int sg = (kt * 4 + lq) ^ (rl & 7);
                bq[nt][kt] = load8(kbuf + rl * 64 + sg * 8);
            }

        const floatx4 zero4 = {0.f, 0.f, 0.f, 0.f};
        floatx4 oacc[4][4];
        float lsum[4] = {0.f, 0.f, 0.f, 0.f};
#pragma unroll
        for (int mt = 0; mt < 4; ++mt)
#pragma unroll
            for (int nt = 0; nt < 4; ++nt) oacc[mt][nt] = zero4;

        const int nss = (2 * jq + 5) >> 2;  // supersteps of 128 k
        const int kmask = 2 * jq;

#pragma unroll 1
        for (int ss = 0; ss < nss; ++ss) {
            const int kbase = ss * 128;
            __syncthreads();  // prior superstep reads (or bq reads) complete
#pragma unroll
            for (int i = 0; i < 4; ++i) {
                int flat = t + i * 256;
                int row = flat >> 3, sg = (flat & 7) ^ (row & 7);
                gload_lds16(Kb + (size_t)(kbase + row) * D + sg * 8, kbuf + flat * 8);
            }
#pragma unroll
            for (int i = 0; i < 4; ++i) {
                int flat = t + i * 256;
                int row = flat >> 4, sg = (flat & 15) ^ (row & 15);
                gload_lds16(Vb + (size_t)row * S + kbase + sg * 8, vbuf + flat * 8);
            }
            __syncthreads();  // staging visible (drains DMA)

            const int ks = ss * 4 + w;   // this wave's k-step (may overshoot: all-masked)
            const int k0 = ks * 32;
            short8 bk[2][2];
#pragma unroll
            for (int mt = 0; mt < 2; ++mt)
#pragma unroll
                for (int kt = 0; kt < 2; ++kt) {
                    const int rl = w * 32 + mt * 16 + lr;
                    const int sg = (kt * 4 + lq) ^ (rl & 7);
                    bk[mt][kt] = load8(kbuf + rl * 64 + sg * 8);
                }
            floatx4 sacc[2][4];
#pragma unroll
            for (int mt = 0; mt < 2; ++mt)
#pragma unroll
                for (int nt = 0; nt < 4; ++nt) sacc[mt][nt] = zero4;
#pragma unroll
            for (int mt = 0; mt < 2; ++mt)
#pragma unroll
                for (int nt = 0; nt < 4; ++nt)
#pragma unroll
                    for (int kt = 0; kt < 2; ++kt)
                        sacc[mt][nt] = __builtin_amdgcn_mfma_f32_16x16x32_bf16(
                            bk[mt][kt], bq[nt][kt], sacc[mt][nt], 0, 0, 0);
            short4v bv[2][4];
#pragma unroll
            for (int mt = 0; mt < 2; ++mt)
#pragma unroll
                for (int ntd = 0; ntd < 4; ++ntd) {
                    const int rl = ntd * 16 + lr;
                    const int sg = (w * 4 + mt * 2 + (lq >> 1)) ^ (rl & 15);
                    bv[mt][ntd] = load4(vbuf + rl * 128 + sg * 8 + (lq & 1) * 4);
                }
            const bool domask = ks >= kmask;  // wave-uniform (true for overshoot)
            short4v ap[2][4];
#pragma unroll
            for (int mt = 0; mt < 2; ++mt)
#pragma unroll
                for (int nt = 0; nt < 4; ++nt) {
                    float p0 = exp2_fast(sacc[mt][nt][0]);
                    float p1 = exp2_fast(sacc[mt][nt][1]);
                    float p2 = exp2_fast(sacc[mt][nt][2]);
                    float p3 = exp2_fast(sacc[mt][nt][3]);
                    if (domask) {
                        const int qg = q0 + nt * 16 + lr;
                        const int kb2 = k0 + mt * 16 + lq * 4;
                        p0 = (kb2 + 0 <= qg) ? p0 : 0.f;
                        p1 = (kb2 + 1 <= qg) ? p1 : 0.f;
                        p2 = (kb2 + 2 <= qg) ? p2 : 0.f;
                        p3 = (kb2 + 3 <= qg) ? p3 : 0.f;
                    }
                    lsum[nt] += (p0 + p1) + (p2 + p3);
                    S4U u;
                    u.u.x = pack_bf16(p0, p1);
                    u.u.y = pack_bf16(p2, p3);
                    ap[mt][nt] = u.v;
                }
#pragma unroll
            for (int mt = 0; mt < 2; ++mt)
#pragma unroll
                for (int ntq = 0; ntq < 4; ++ntq)
#pragma unroll
                    for (int ntd = 0; ntd < 4; ++ntd)
                        oacc[ntq][ntd] = mfma16(ap[mt][ntq], bv[mt][ntd], oacc[ntq][ntd]);
        }

        // reduce lsum over the 4 lq-quads (q index = nt*16+lr is lr-indexed)
#pragma unroll
        for (int nt = 0; nt < 4; ++nt) {
            float s = lsum[nt];
            s += __shfl_xor(s, 16, 64);
            s += __shfl_xor(s, 32, 64);
            lsum[nt] = s;
        }

        // ---- cross-wave reduce: d in 4 chunks of 16, buf[w][64][20] fp32 ----
        // FULLY UNROLLED: dynamic oacc indexing spills the accumulator to
        // scratch (R5/R6 lesson: 139 MB scratch writes from `unroll 1`).
        const int row = t >> 2, c0 = (t & 3) * 4;
        __hip_bfloat16* Ob = O + ((size_t)b * S) * D + h * 64;
        float inv = 0.f;
        __syncthreads();  // k-loop LDS reads complete before overwrite
#pragma unroll
        for (int chunk = 0; chunk < 4; ++chunk) {
#pragma unroll
            for (int mtq = 0; mtq < 4; ++mtq)
#pragma unroll
                for (int r = 0; r < 4; ++r)
                    buf[w * 1280 + (mtq * 16 + lq * 4 + r) * 20 + lr] = oacc[mtq][chunk][r];
            if (chunk == 0 && lq == 0) {
#pragma unroll
                for (int nt = 0; nt < 4; ++nt)
                    buf[w * 1280 + (nt * 16 + lr) * 20 + 16] = lsum[nt];
            }
            __syncthreads();
            if (chunk == 0) {
                float Lt = buf[row * 20 + 16] + buf[1280 + row * 20 + 16] +
                           buf[2560 + row * 20 + 16] + buf[3840 + row * 20 + 16];
                inv = 1.f / Lt;
            }
            float4 a = {0.f, 0.f, 0.f, 0.f};
#pragma unroll
            for (int w2 = 0; w2 < 4; ++w2) {
                float4 v = *reinterpret_cast<const float4*>(buf + w2 * 1280 + row * 20 + c0);
                a.x += v.x; a.y += v.y; a.z += v.z; a.w += v.w;
            }
            uint2 d;
            d.x = pack_bf16(a.x * inv, a.y * inv);
            d.y = pack_bf16(a.z * inv, a.w * inv);
            *reinterpret_cast<uint2*>(Ob + (size_t)(q0 + row) * D + chunk * 16 + c0) = d;
            if (chunk < 3) __syncthreads();
        }
    }
}

extern "C" void kernel_launch(void* const* d_in, const int* in_sizes, int n_in,
                              void* d_out, int out_size, void* d_ws, size_t ws_size,
                              hipStream_t stream) {
    const float* hs  = (const float*)d_in[0];  // [2,2048,1024]
    const float* wq  = (const float*)d_in[1];  // [1024,1024]
    const float* wk  = (const float*)d_in[2];
    const float* wv  = (const float*)d_in[3];
    const float* wo  = (const float*)d_in[4];
    const float* qkf = (const float*)d_in[5];  // scalar

    char* ws = (char*)d_ws;
    const size_t MB = 1024 * 1024;
    __hip_bfloat16* Xb  = (__hip_bfloat16*)(ws);            // 8 MB  [4096,1024]
    __hip_bfloat16* Wqb = (__hip_bfloat16*)(ws + 8 * MB);   // 2 MB each: Wq,Wk,Wv,Wo
    __hip_bfloat16* Wob = (__hip_bfloat16*)(ws + 14 * MB);
    __hip_bfloat16* Qb  = (__hip_bfloat16*)(ws + 16 * MB);  // 8 MB [4096,1024]
    __hip_bfloat16* Kb  = (__hip_bfloat16*)(ws + 24 * MB);  // 8 MB [4096,1024]
    __hip_bfloat16* Vt  = (__hip_bfloat16*)(ws + 40 * MB);  // 8 MB [B,1024,2048]
    __hip_bfloat16* Ab  = (__hip_bfloat16*)(ws + 48 * MB);  // 8 MB attn out

    cast_all<<<dim3(4096, 2), 256, 0, stream>>>(hs, wq, wk, wv, wo, Xb, Wqb);

    // Q,K (fused hypersphere norm; Q scaled by qkf*log2e) + V stored transposed
    gemm_qkv<<<dim3(32, 8, 3), 256, 0, stream>>>(Xb, Wqb, Qb, Kb, Vt, qkf);

    flash_attn<<<512, 256, 0, stream>>>(Qb, Kb, Vt, Ab);

    gemm_out<<<dim3(64, 8), 256, 0, stream>>>(Ab, Wob, (float*)d_out);
}